// Round 1
// baseline (259.837 us; speedup 1.0000x reference)
//
#include <hip/hip_runtime.h>

// ElasticEmbedding: out[t,:] = residual_embedding[lower_bound(ridx, x[t])] if
// x[t] ∈ ridx else pretrained_embedding[x[t]].  D = 128 floats (= 32 x 16B).
//
// R6 structure: ONE fused kernel, zero workspace. ridx is sorted, so the
// remap table + resolve pass (R5) are replaced by a branchless 15-step
// lower-bound binary search done inline per token. The search is uniform
// across each 32-lane group (all lanes same address -> broadcast loads), its
// top ~8 levels stay L1-hot, the rest are L2-resident (80 KB). The load
// chain per token becomes x -> 15 cached searches -> row load; with 128
// tokens in flight/CU this stays hidden behind the 134 MB NT-store stream.
// Gather body unchanged from R5 (32 lanes/token, 16B/lane, UNROLL 2 strided,
// low VGPR for max waves, NT stores keep output from evicting tables).

#define BLOCK 256
#define UNROLL 2

typedef __attribute__((ext_vector_type(4))) float f4;

__global__ __launch_bounds__(BLOCK, 8) void fused_gather_kernel(
        const int* __restrict__ x,     // [n_tokens] token ids
        const int* __restrict__ ridx,  // [R] sorted residual vocab ids
        const f4* __restrict__ pre,    // [V, 32] 16B chunks
        const f4* __restrict__ res,    // [R, 32]
        f4* __restrict__ out,          // [n_tokens, 32]
        int n_tokens, int n_groups, int R, int step0) {
    int g    = (blockIdx.x * BLOCK + threadIdx.x) >> 5;   // 32-lane group id
    int lane = threadIdx.x & 31;

    int tok[UNROLL], t[UNROLL];
    bool ok[UNROLL];
    #pragma unroll
    for (int k = 0; k < UNROLL; ++k) {
        tok[k] = g + k * n_groups;
        ok[k]  = tok[k] < n_tokens;
        t[k]   = ok[k] ? x[tok[k]] : 0;   // broadcast load (group-uniform)
    }

    // Branchless lower bound: lo = #elements < t. The two UNROLL chains are
    // independent -> interleaved for MLP. step0 = largest pow2 <= R, so
    // guarded descent covers any index in [0, R].
    int lo[UNROLL] = {0};
    for (int step = step0; step > 0; step >>= 1) {
        #pragma unroll
        for (int k = 0; k < UNROLL; ++k) {
            int cand = lo[k] + step;
            if (cand <= R && ridx[cand - 1] < t[k]) lo[k] = cand;
        }
    }

    const f4* src[UNROLL];
    #pragma unroll
    for (int k = 0; k < UNROLL; ++k) {
        bool hit = (lo[k] < R) && (ridx[lo[k]] == t[k]);
        src[k] = hit ? res + (size_t)lo[k] * 32
                     : pre + (size_t)t[k] * 32;
    }

    f4 val[UNROLL];
    #pragma unroll
    for (int k = 0; k < UNROLL; ++k)
        if (ok[k]) val[k] = src[k][lane];   // 2 outstanding 16B loads/thread

    #pragma unroll
    for (int k = 0; k < UNROLL; ++k)
        if (ok[k])
            __builtin_nontemporal_store(val[k],
                &out[(size_t)tok[k] * 32 + lane]);
}

extern "C" void kernel_launch(void* const* d_in, const int* in_sizes, int n_in,
                              void* d_out, int out_size, void* d_ws, size_t ws_size,
                              hipStream_t stream) {
    const int* x    = (const int*)d_in[0];     // [B*S] token ids
    const int* ridx = (const int*)d_in[1];     // [R] sorted residual ids
    const f4*  pre  = (const f4*)d_in[2];      // [V, D/4]
    const f4*  res  = (const f4*)d_in[3];      // [R, D/4]
    f4*        out  = (f4*)d_out;

    const int n_tokens = in_sizes[0];
    const int R        = in_sizes[1];
    (void)n_in; (void)out_size; (void)d_ws; (void)ws_size;

    int step0 = 1;
    while ((step0 << 1) <= R) step0 <<= 1;     // largest pow2 <= R (16384)

    int n_groups = (n_tokens + UNROLL - 1) / UNROLL;   // 131072
    int threads  = n_groups * 32;
    int blocks   = (threads + BLOCK - 1) / BLOCK;      // 16384
    fused_gather_kernel<<<blocks, BLOCK, 0, stream>>>(x, ridx, pre, res, out,
                                                      n_tokens, n_groups, R,
                                                      step0);
}

// Round 2
// 223.761 us; speedup vs baseline: 1.1612x; 1.1612x over previous
//
#include <hip/hip_runtime.h>

// ElasticEmbedding: out[t,:] = residual_embedding[lower_bound(ridx, x[t])] if
// x[t] ∈ ridx else pretrained_embedding[x[t]].  D = 128 floats (= 32 x 16B).
//
// R7 structure: ONE fused kernel, zero workspace, 32-ary LANE-PARALLEL search
// (R6's 15-deep serial binary search was latency-bound: 1.7 TB/s @ 21% HBM).
// The 32 lanes serving a token probe 32 positions at once; ballot+popc
// narrows 20000 -> 625 -> 21 -> exact in 3 levels. Level-1 probe positions
// are token-independent -> hoisted to registers once (zero chain cost).
// Dependent chain per token: x -> ballot -> lv2 probe -> lv3 probe -> shfl
// -> row load  (~2000 cy vs ~5-6K for binary search). UNROLL 4 (VGPR was 12,
// lots of headroom) doubles in-flight tokens. NT stores keep the 134 MB
// output stream from evicting the tables.
//
// Level strides (host-computed): s1 = ceil(R/32), s2 = ceil((s1+1)/31).
// Coverage proof: after lv1, lo ∈ [base1, base1+s1]; after lv2,
// lo ∈ [base2, base2+s2] with s2 <= 31 (holds for R <= ~30k; R = 20000
// gives s1=625, s2=21), so 32 consecutive lv3 probes always cover.

#define BLOCK 256
#define UNROLL 4

typedef __attribute__((ext_vector_type(4))) float f4;

__global__ __launch_bounds__(BLOCK, 8) void fused_gather_kernel(
        const int* __restrict__ x,     // [n_tokens] token ids
        const int* __restrict__ ridx,  // [R] sorted residual vocab ids
        const f4* __restrict__ pre,    // [V, 32] 16B chunks
        const f4* __restrict__ res,    // [R, 32]
        f4* __restrict__ out,          // [n_tokens, 32]
        int n_tokens, int n_groups, int R, int s1, int s2) {
    int g      = (blockIdx.x * BLOCK + threadIdx.x) >> 5;  // 32-lane group id
    int lane   = threadIdx.x & 31;
    unsigned gshift = threadIdx.x & 32;  // which half of the 64-bit ballot

    // Level-1 samples: token-independent, loaded ONCE per thread. These 32
    // cachelines are L1-hot for the whole kernel.
    int  p1   = lane * s1;
    bool p1ok = p1 < R;
    int  v1   = ridx[p1ok ? p1 : (R - 1)];

    int tok[UNROLL], t[UNROLL];
    bool ok[UNROLL];
    #pragma unroll
    for (int k = 0; k < UNROLL; ++k) {
        tok[k] = g + k * n_groups;
        ok[k]  = tok[k] < n_tokens;
        t[k]   = ok[k] ? x[tok[k]] : 0;   // group-uniform broadcast load
    }

    // Level 1: pure ballot over preloaded samples (no memory on the chain).
    int base1[UNROLL];
    #pragma unroll
    for (int k = 0; k < UNROLL; ++k) {
        unsigned long long m = __ballot(p1ok && (v1 < t[k]));
        int c1 = __popc((unsigned)(m >> gshift));
        base1[k] = (c1 > 0) ? (c1 - 1) * s1 : 0;
    }

    // Level 2: 32 probes at stride s2 (4 independent loads -> MLP).
    int v2[UNROLL]; bool q2ok[UNROLL];
    #pragma unroll
    for (int k = 0; k < UNROLL; ++k) {
        int q    = base1[k] + lane * s2;
        q2ok[k]  = q < R;
        v2[k]    = ridx[q2ok[k] ? q : (R - 1)];
    }
    int base2[UNROLL];
    #pragma unroll
    for (int k = 0; k < UNROLL; ++k) {
        unsigned long long m = __ballot(q2ok[k] && (v2[k] < t[k]));
        int c2 = __popc((unsigned)(m >> gshift));
        base2[k] = base1[k] + ((c2 > 0) ? (c2 - 1) * s2 : 0);
    }

    // Level 3: 32 consecutive elements (one coalesced 128 B read per token).
    int v3[UNROLL];
    #pragma unroll
    for (int k = 0; k < UNROLL; ++k) {
        int q = base2[k] + lane;
        v3[k] = ridx[(q < R) ? q : (R - 1)];
    }
    const f4* src[UNROLL];
    #pragma unroll
    for (int k = 0; k < UNROLL; ++k) {
        int q = base2[k] + lane;
        unsigned long long m = __ballot((q < R) && (v3[k] < t[k]));
        int c3 = __popc((unsigned)(m >> gshift));
        int lo = base2[k] + c3;                       // = lower_bound
        int vlo = __shfl(v3[k], (int)(gshift + c3), 64);  // ridx[lo], no load
        bool hit = (lo < R) && (vlo == t[k]);
        src[k] = hit ? res + (size_t)lo * 32
                     : pre + (size_t)t[k] * 32;
    }

    // Row gather: 4 outstanding 16 B loads/thread, then NT stores.
    f4 val[UNROLL];
    #pragma unroll
    for (int k = 0; k < UNROLL; ++k)
        if (ok[k]) val[k] = src[k][lane];

    #pragma unroll
    for (int k = 0; k < UNROLL; ++k)
        if (ok[k])
            __builtin_nontemporal_store(val[k],
                &out[(size_t)tok[k] * 32 + lane]);
}

extern "C" void kernel_launch(void* const* d_in, const int* in_sizes, int n_in,
                              void* d_out, int out_size, void* d_ws, size_t ws_size,
                              hipStream_t stream) {
    const int* x    = (const int*)d_in[0];     // [B*S] token ids
    const int* ridx = (const int*)d_in[1];     // [R] sorted residual ids
    const f4*  pre  = (const f4*)d_in[2];      // [V, D/4]
    const f4*  res  = (const f4*)d_in[3];      // [R, D/4]
    f4*        out  = (f4*)d_out;

    const int n_tokens = in_sizes[0];
    const int R        = in_sizes[1];
    (void)n_in; (void)out_size; (void)d_ws; (void)ws_size;

    const int s1 = (R + 31) / 32;        // ceil(R/32): 32 lv1 buckets
    const int s2 = (s1 + 31) / 31;       // 31*s2 >= s1+1: lv2 coverage

    int n_groups = (n_tokens + UNROLL - 1) / UNROLL;   // 65536
    int threads  = n_groups * 32;
    int blocks   = (threads + BLOCK - 1) / BLOCK;      // 8192
    fused_gather_kernel<<<blocks, BLOCK, 0, stream>>>(x, ridx, pre, res, out,
                                                      n_tokens, n_groups, R,
                                                      s1, s2);
}

// Round 3
// 210.028 us; speedup vs baseline: 1.2372x; 1.0654x over previous
//
#include <hip/hip_runtime.h>

// ElasticEmbedding: out[t,:] = residual_embedding[remap[x[t]]] if x[t] is a
// residual id else pretrained_embedding[x[t]].  D = 128 floats (= 32 x 16B).
//
// R8 structure: remap table (search variants R6/R7 lose: a remap lookup is
// ONE L2 line/token vs a 32-line lv2 probe ≈ 537 MB L2 traffic + ballot VALU).
//   1. hipMemsetAsync ws -> remap = -1      (no custom fill dispatch)
//   2. scatter_remap: remap[ridx[i]] = i    (80 KB, ~2 us)
//   3. gather with remap lookup FUSED: t = x[tok]; r = remap[t]; pick row.
// vs R5: resolve's 2 MB combined round-trip + 2 dispatches + gaps removed;
// the remap load joins the gather chain (x -> remap -> row, ~250 cy extra,
// hidden by TLP at 80% occupancy / 8 waves/SIMD).
// Gather body = R5's proven structure: 32 lanes/token, 16B/lane, UNROLL 2
// strided, low VGPR for max waves, NT stores keep the 134 MB output stream
// from evicting the tables in L2/L3.

#define BLOCK 256
#define UNROLL 2

typedef __attribute__((ext_vector_type(4))) float f4;

__global__ void scatter_remap_kernel(int* __restrict__ remap,
                                     const int* __restrict__ ridx, int R) {
    int i = blockIdx.x * blockDim.x + threadIdx.x;
    if (i < R) remap[ridx[i]] = i;
}

__global__ __launch_bounds__(BLOCK, 8) void gather_kernel(
        const int* __restrict__ x,      // [n_tokens] token ids
        const int* __restrict__ remap,  // [V] residual row or -1
        const f4* __restrict__ pre,     // [V, 32] 16B chunks
        const f4* __restrict__ res,     // [R, 32]
        f4* __restrict__ out,           // [n_tokens, 32]
        int n_tokens, int n_groups) {
    int g    = (blockIdx.x * BLOCK + threadIdx.x) >> 5;   // 32-lane group id
    int lane = threadIdx.x & 31;

    int tok[UNROLL], t[UNROLL];
    bool ok[UNROLL];
    #pragma unroll
    for (int k = 0; k < UNROLL; ++k) {
        tok[k] = g + k * n_groups;
        ok[k]  = tok[k] < n_tokens;
        t[k]   = ok[k] ? x[tok[k]] : 0;     // group-uniform broadcast load
    }

    int r[UNROLL];
    #pragma unroll
    for (int k = 0; k < UNROLL; ++k)        // 2 independent L2-resident loads
        r[k] = ok[k] ? remap[t[k]] : -1;    // (400 KB table, 1 line/token)

    const f4* src[UNROLL];
    #pragma unroll
    for (int k = 0; k < UNROLL; ++k)
        src[k] = (r[k] >= 0) ? res + (size_t)r[k] * 32
                             : pre + (size_t)t[k] * 32;

    f4 val[UNROLL];
    #pragma unroll
    for (int k = 0; k < UNROLL; ++k)
        if (ok[k]) val[k] = src[k][lane];   // 2 outstanding 16B loads/thread

    #pragma unroll
    for (int k = 0; k < UNROLL; ++k)
        if (ok[k])
            __builtin_nontemporal_store(val[k],
                &out[(size_t)tok[k] * 32 + lane]);
}

extern "C" void kernel_launch(void* const* d_in, const int* in_sizes, int n_in,
                              void* d_out, int out_size, void* d_ws, size_t ws_size,
                              hipStream_t stream) {
    const int* x    = (const int*)d_in[0];     // [B*S] token ids
    const int* ridx = (const int*)d_in[1];     // [R] sorted residual ids
    const f4*  pre  = (const f4*)d_in[2];      // [V, D/4]
    const f4*  res  = (const f4*)d_in[3];      // [R, D/4]
    f4*        out  = (f4*)d_out;

    const int n_tokens = in_sizes[0];
    const int R        = in_sizes[1];
    const int D        = in_sizes[3] / R;      // 128
    const int V        = in_sizes[2] / D;      // 100000
    (void)n_in; (void)out_size; (void)ws_size;

    int* remap = (int*)d_ws;                   // V ints = 400 KB

    hipMemsetAsync(remap, 0xFF, (size_t)V * sizeof(int), stream);  // -1 fill
    scatter_remap_kernel<<<(R + 255) / 256, 256, 0, stream>>>(remap, ridx, R);

    int n_groups = (n_tokens + UNROLL - 1) / UNROLL;   // 131072
    int threads  = n_groups * 32;
    int blocks   = (threads + BLOCK - 1) / BLOCK;      // 16384
    gather_kernel<<<blocks, BLOCK, 0, stream>>>(x, remap, pre, res, out,
                                                n_tokens, n_groups);
}

// Round 4
// 204.129 us; speedup vs baseline: 1.2729x; 1.0289x over previous
//
#include <hip/hip_runtime.h>

// ElasticEmbedding: out[t,:] = residual_embedding[remap[x[t]]] if x[t] is a
// residual id else pretrained_embedding[x[t]].  D = 128 floats (= 32 x 16B).
//
// R9 structure: 3 dispatches (memset remap, scatter, fused gather).
//   R8 post-mortem: fusing remap into the gather made the chain 3-deep
//   (x -> remap -> row) and UNROLL 2 strided couldn't hide the extra L2 hop
//   (gather 49 -> 60 us). Fix: UNROLL 4, SEQUENTIAL token blocking:
//   - group g owns tokens 4g..4g+3 -> one int4 broadcast load for 4 ids
//   - 4 independent remap loads, then 4 independent row loads (width-4 MLP)
//   - 4 output rows contiguous: 2 KB/group, 16 KB/block coalesced NT stores
//   VGPR ~48 (<=64 keeps 8 blocks/CU = 2048 thr). Roofline: 198 MB HBM
//   (64 fetch after L3 row-reuse ~2x + 134 write) ~= 40-45 us mixed-traffic.
// NT stores keep the 134 MB output stream from evicting tables in L2/L3.

#define BLOCK 256
#define UNROLL 4

typedef __attribute__((ext_vector_type(4))) float f4;

__global__ void scatter_remap_kernel(int* __restrict__ remap,
                                     const int* __restrict__ ridx, int R) {
    int i = blockIdx.x * blockDim.x + threadIdx.x;
    if (i < R) remap[ridx[i]] = i;
}

__global__ __launch_bounds__(BLOCK, 8) void gather_kernel(
        const int* __restrict__ x,      // [n_tokens] token ids
        const int* __restrict__ remap,  // [V] residual row or -1
        const f4* __restrict__ pre,     // [V, 32] 16B chunks
        const f4* __restrict__ res,     // [R, 32]
        f4* __restrict__ out,           // [n_tokens, 32]
        int n_tokens) {
    int g    = (blockIdx.x * BLOCK + threadIdx.x) >> 5;   // 32-lane group id
    int lane = threadIdx.x & 31;
    int tb   = g * UNROLL;                                // first token
    if (tb >= n_tokens) return;

    // 4 token ids in ONE 16B broadcast load (group-uniform).
    int t[UNROLL];
    if (tb + UNROLL <= n_tokens) {
        int4 xv = *reinterpret_cast<const int4*>(x + tb);
        t[0] = xv.x; t[1] = xv.y; t[2] = xv.z; t[3] = xv.w;
    } else {
        #pragma unroll
        for (int k = 0; k < UNROLL; ++k)
            t[k] = (tb + k < n_tokens) ? x[tb + k] : 0;
    }

    // 4 independent L2-resident remap loads (400 KB table, 1 line/token).
    int r[UNROLL];
    #pragma unroll
    for (int k = 0; k < UNROLL; ++k)
        r[k] = remap[t[k]];

    const f4* src[UNROLL];
    #pragma unroll
    for (int k = 0; k < UNROLL; ++k)
        src[k] = (r[k] >= 0) ? res + (size_t)r[k] * 32
                             : pre + (size_t)t[k] * 32;

    // 4 outstanding 16B row loads/thread.
    f4 val[UNROLL];
    #pragma unroll
    for (int k = 0; k < UNROLL; ++k)
        val[k] = src[k][lane];

    // Contiguous 2 KB/group NT stores.
    #pragma unroll
    for (int k = 0; k < UNROLL; ++k)
        if (tb + k < n_tokens)
            __builtin_nontemporal_store(val[k],
                &out[(size_t)(tb + k) * 32 + lane]);
}

extern "C" void kernel_launch(void* const* d_in, const int* in_sizes, int n_in,
                              void* d_out, int out_size, void* d_ws, size_t ws_size,
                              hipStream_t stream) {
    const int* x    = (const int*)d_in[0];     // [B*S] token ids
    const int* ridx = (const int*)d_in[1];     // [R] sorted residual ids
    const f4*  pre  = (const f4*)d_in[2];      // [V, D/4]
    const f4*  res  = (const f4*)d_in[3];      // [R, D/4]
    f4*        out  = (f4*)d_out;

    const int n_tokens = in_sizes[0];
    const int R        = in_sizes[1];
    const int D        = in_sizes[3] / R;      // 128
    const int V        = in_sizes[2] / D;      // 100000
    (void)n_in; (void)out_size; (void)ws_size;

    int* remap = (int*)d_ws;                   // V ints = 400 KB

    hipMemsetAsync(remap, 0xFF, (size_t)V * sizeof(int), stream);  // -1 fill
    scatter_remap_kernel<<<(R + 255) / 256, 256, 0, stream>>>(remap, ridx, R);

    int n_groups = (n_tokens + UNROLL - 1) / UNROLL;   // 65536
    int threads  = n_groups * 32;
    int blocks   = (threads + BLOCK - 1) / BLOCK;      // 8192
    gather_kernel<<<blocks, BLOCK, 0, stream>>>(x, remap, pre, res, out,
                                                n_tokens);
}

// Round 5
// 203.946 us; speedup vs baseline: 1.2740x; 1.0009x over previous
//
#include <hip/hip_runtime.h>

// ElasticEmbedding: out[t,:] = residual_embedding[remap[x[t]]] if x[t] is a
// residual id else pretrained_embedding[x[t]].  D = 128 floats (= 32 x 16B).
//
// R10 structure: 3 dispatches (memset remap, scatter, fused gather).
//   Ledger (harness floor ~143 us): R8 gather ~60, R9 (UNROLL 4 seq) ~54.
//   Remaining slack vs ~40-45 us mixed-traffic floor is latency exposure of
//   the x -> remap -> row chain. R10:
//   - UNROLL 6: chain width 6, 6 KB row data in flight per wave. VGPR ~56,
//     still <= 64 so __launch_bounds__(256,8) keeps 8 waves/SIMD (R4 lesson:
//     crossing 64 VGPR halves occupancy -> never again).
//   - remap as uint16 (sentinel 0xFFFF via memset, valid r < 20000): table
//     400 -> 200 KB, L2-resident on every XCD even under stream pressure.
//   - token ids via 3x int2 loads (byte offset 24g, always 8B-aligned);
//     output rows contiguous: 3 KB/group coalesced NT stores.
// NT stores keep the 134 MB output stream from evicting tables in L2/L3.
// Traffic floor: 64 MB fetch (unique rows + x, repeats L3-hit) + 134 MB
// write = 198 MB. If this round doesn't move, gather is HBM-bound: roofline.

#define BLOCK 256
#define UNROLL 6

typedef __attribute__((ext_vector_type(4))) float f4;

__global__ void scatter_remap_kernel(unsigned short* __restrict__ remap,
                                     const int* __restrict__ ridx, int R) {
    int i = blockIdx.x * blockDim.x + threadIdx.x;
    if (i < R) remap[ridx[i]] = (unsigned short)i;
}

__global__ __launch_bounds__(BLOCK, 8) void gather_kernel(
        const int* __restrict__ x,               // [n_tokens] token ids
        const unsigned short* __restrict__ remap,// [V] residual row or 0xFFFF
        const f4* __restrict__ pre,              // [V, 32] 16B chunks
        const f4* __restrict__ res,              // [R, 32]
        f4* __restrict__ out,                    // [n_tokens, 32]
        int n_tokens, int R) {
    int g    = (blockIdx.x * BLOCK + threadIdx.x) >> 5;   // 32-lane group id
    int lane = threadIdx.x & 31;
    int tb   = g * UNROLL;                                // first token
    if (tb >= n_tokens) return;

    // 6 token ids via three 8B broadcast loads (group-uniform, always
    // 8B-aligned: byte offset = 24*g).
    int t[UNROLL];
    if (tb + UNROLL <= n_tokens) {
        const int2* xp = reinterpret_cast<const int2*>(x + tb);
        int2 a = xp[0], b = xp[1], c = xp[2];
        t[0] = a.x; t[1] = a.y; t[2] = b.x;
        t[3] = b.y; t[4] = c.x; t[5] = c.y;
    } else {
        #pragma unroll
        for (int k = 0; k < UNROLL; ++k)
            t[k] = (tb + k < n_tokens) ? x[tb + k] : 0;
    }

    // 6 independent L2-resident remap loads (200 KB table, 1 line/token).
    unsigned r[UNROLL];
    #pragma unroll
    for (int k = 0; k < UNROLL; ++k)
        r[k] = remap[t[k]];

    const f4* src[UNROLL];
    #pragma unroll
    for (int k = 0; k < UNROLL; ++k)
        src[k] = (r[k] < (unsigned)R) ? res + (size_t)r[k] * 32
                                      : pre + (size_t)t[k] * 32;

    // 6 outstanding 16B row loads/thread (6 KB/wave in flight).
    f4 val[UNROLL];
    #pragma unroll
    for (int k = 0; k < UNROLL; ++k)
        val[k] = src[k][lane];

    // Contiguous 3 KB/group NT stores.
    #pragma unroll
    for (int k = 0; k < UNROLL; ++k)
        if (tb + k < n_tokens)
            __builtin_nontemporal_store(val[k],
                &out[(size_t)(tb + k) * 32 + lane]);
}

extern "C" void kernel_launch(void* const* d_in, const int* in_sizes, int n_in,
                              void* d_out, int out_size, void* d_ws, size_t ws_size,
                              hipStream_t stream) {
    const int* x    = (const int*)d_in[0];     // [B*S] token ids
    const int* ridx = (const int*)d_in[1];     // [R] sorted residual ids
    const f4*  pre  = (const f4*)d_in[2];      // [V, D/4]
    const f4*  res  = (const f4*)d_in[3];      // [R, D/4]
    f4*        out  = (f4*)d_out;

    const int n_tokens = in_sizes[0];
    const int R        = in_sizes[1];
    const int D        = in_sizes[3] / R;      // 128
    const int V        = in_sizes[2] / D;      // 100000
    (void)n_in; (void)out_size; (void)ws_size;

    unsigned short* remap = (unsigned short*)d_ws;   // V ushorts = 200 KB

    hipMemsetAsync(remap, 0xFF, (size_t)V * sizeof(unsigned short), stream);
    scatter_remap_kernel<<<(R + 255) / 256, 256, 0, stream>>>(remap, ridx, R);

    int n_groups = (n_tokens + UNROLL - 1) / UNROLL;   // 43691
    int threads  = n_groups * 32;
    int blocks   = (threads + BLOCK - 1) / BLOCK;      // 5462
    gather_kernel<<<blocks, BLOCK, 0, stream>>>(x, remap, pre, res, out,
                                                n_tokens, R);
}